// Round 6
// baseline (170.493 us; speedup 1.0000x reference)
//
#include <hip/hip_runtime.h>
#include <hip/hip_bf16.h>

#define D 64   // feature dim == units == 64
#define R 16   // counter replication factor (kills atomic contention)

// ---------------------------------------------------------------------------
// Fused: blocks [0, gemmTiles) compute Z = emb @ W (stored bf16); remaining
// blocks count degrees into 16-way replicated counters and record each edge's
// rank within its (dst, replica) sub-bucket.  Replication drops same-address
// atomic chains from avg 16 to avg 1 (uncontended TCC RMW rate).
// ---------------------------------------------------------------------------
__global__ __launch_bounds__(256) void gemm_count(
    const float* __restrict__ emb,
    const float* __restrict__ W,
    __hip_bfloat16* __restrict__ Zb,
    const int*   __restrict__ dst,
    int*         __restrict__ counts,   // [N*R]
    int*         __restrict__ rank,     // [E]
    int N, int E, int gemmTiles)
{
    if ((int)blockIdx.x >= gemmTiles) {
        int e = ((int)blockIdx.x - gemmTiles) * 256 + threadIdx.x;
        if (e < E) {
            int idx = (dst[e] << 4) | (e & (R - 1));
            rank[e] = atomicAdd(&counts[idx], 1);
        }
        return;
    }

    const int lane = threadIdx.x & 63;
    const int wave = threadIdx.x >> 6;

    float wcol[D];
#pragma unroll
    for (int k = 0; k < D; ++k) wcol[k] = W[k * D + lane];

    __shared__ float At[64 * D];
    const int row0 = blockIdx.x * 64;

    for (int i = threadIdx.x; i < 1024; i += 256) {
        int r  = i >> 4;
        int gr = row0 + r;
        float4 v;
        if (gr < N) v = reinterpret_cast<const float4*>(emb)[(size_t)gr * 16 + (i & 15)];
        else        v = float4{0.f, 0.f, 0.f, 0.f};
        reinterpret_cast<float4*>(At)[i] = v;
    }
    __syncthreads();

    for (int rr = 0; rr < 16; ++rr) {
        int r  = wave * 16 + rr;
        int gr = row0 + r;
        if (gr >= N) break;
        const float4* arow = reinterpret_cast<const float4*>(At + r * D);
        float acc = 0.f;
#pragma unroll
        for (int k4 = 0; k4 < 16; ++k4) {
            float4 a = arow[k4];
            acc = fmaf(a.x, wcol[4 * k4 + 0], acc);
            acc = fmaf(a.y, wcol[4 * k4 + 1], acc);
            acc = fmaf(a.z, wcol[4 * k4 + 2], acc);
            acc = fmaf(a.w, wcol[4 * k4 + 3], acc);
        }
        Zb[(size_t)gr * D + lane] = __float2bfloat16(acc);  // RNE
    }
}

// ---------------------------------------------------------------------------
// Two-level scan over the N*R (padded) counter array: 4096 elements per block
// (256 thr x 16), per-block totals in partials (<=256, scanned inline by
// consumers).  Grid exactly covers the padded array (memset to 0) — no guards.
// ---------------------------------------------------------------------------
__global__ __launch_bounds__(256) void scan_blocks2(
    const int* __restrict__ counts, int* __restrict__ offsets,
    int* __restrict__ partials)
{
    __shared__ int sh[256];
    const int t    = threadIdx.x;
    const int base = blockIdx.x * 4096 + t * 16;

    int v[16], ps[16];
#pragma unroll
    for (int k = 0; k < 4; ++k) {
        int4 x = reinterpret_cast<const int4*>(counts + base)[k];
        v[4*k+0] = x.x; v[4*k+1] = x.y; v[4*k+2] = x.z; v[4*k+3] = x.w;
    }
    int s = 0;
#pragma unroll
    for (int k = 0; k < 16; ++k) { ps[k] = s; s += v[k]; }  // exclusive local
    sh[t] = s;
    __syncthreads();
    for (int off = 1; off < 256; off <<= 1) {
        int x = (t >= off) ? sh[t - off] : 0;
        __syncthreads();
        sh[t] += x;
        __syncthreads();
    }
    const int excl = sh[t] - s;
#pragma unroll
    for (int k = 0; k < 4; ++k) {
        int4 o;
        o.x = excl + ps[4*k+0]; o.y = excl + ps[4*k+1];
        o.z = excl + ps[4*k+2]; o.w = excl + ps[4*k+3];
        reinterpret_cast<int4*>(offsets + base)[k] = o;
    }
    if (t == 255) partials[blockIdx.x] = sh[255];
}

// Inline exclusive scan of <=256 chunk partials into LDS (all 256 threads).
__device__ __forceinline__ void scan_partials_lds256(
    const int* __restrict__ partials, int nb, int* sp)
{
    const int t    = threadIdx.x;
    const int orig = (t < nb) ? partials[t] : 0;
    sp[t] = orig;
    __syncthreads();
    for (int off = 1; off < 256; off <<= 1) {
        int x = (t >= off) ? sp[t - off] : 0;
        __syncthreads();
        sp[t] += x;
        __syncthreads();
    }
    int incl = sp[t];
    __syncthreads();
    sp[t] = incl - orig;  // exclusive
    __syncthreads();
}

// Fill: NO atomics.  csr[offset(dst,replica)+rank] = {src, w_bits}.
// 4 edges per thread via int4/float4 loads for store ILP.
__global__ __launch_bounds__(256) void fill_csr(
    const int*   __restrict__ dst,
    const int*   __restrict__ rank,
    const int*   __restrict__ esrc,
    const float* __restrict__ ew,
    const int*   __restrict__ offsets,
    const int*   __restrict__ partials,
    int2*        __restrict__ csr,
    int E, int nb)
{
    __shared__ int sp[256];
    scan_partials_lds256(partials, nb, sp);

    const int E4 = E >> 2;
    int i = blockIdx.x * 256 + threadIdx.x;
    if (i < E4) {
        int4   d4 = reinterpret_cast<const int4*>(dst)[i];
        int4   r4 = reinterpret_cast<const int4*>(rank)[i];
        int4   s4 = reinterpret_cast<const int4*>(esrc)[i];
        float4 w4 = reinterpret_cast<const float4*>(ew)[i];
        const int e0 = i * 4;
        int ix = (d4.x << 4) | ((e0 + 0) & (R - 1));
        int iy = (d4.y << 4) | ((e0 + 1) & (R - 1));
        int iz = (d4.z << 4) | ((e0 + 2) & (R - 1));
        int iw = (d4.w << 4) | ((e0 + 3) & (R - 1));
        csr[offsets[ix] + sp[ix >> 12] + r4.x] = make_int2(s4.x, __float_as_int(w4.x));
        csr[offsets[iy] + sp[iy >> 12] + r4.y] = make_int2(s4.y, __float_as_int(w4.y));
        csr[offsets[iz] + sp[iz >> 12] + r4.z] = make_int2(s4.z, __float_as_int(w4.z));
        csr[offsets[iw] + sp[iw >> 12] + r4.w] = make_int2(s4.w, __float_as_int(w4.w));
    }
    // tail (E not a multiple of 4)
    if (blockIdx.x == 0 && threadIdx.x == 0) {
        for (int e = E & ~3; e < E; ++e) {
            int ix = (dst[e] << 4) | (e & (R - 1));
            csr[offsets[ix] + sp[ix >> 12] + rank[e]] =
                make_int2(esrc[e], __float_as_int(ew[e]));
        }
    }
}

// ---------------------------------------------------------------------------
// Gather: one wave per node, 4 edges in flight per wave.
// lane = (slot, q): slot = lane>>4 owns every 4th edge, q = lane&15 owns
// Z-row bf16 elements [4q..4q+3] (ushort4 = 8 B; 16 lanes cover the 128 B
// row).  1-deep csr prefetch keeps >=2 loads in flight per slot.
// ---------------------------------------------------------------------------
__global__ __launch_bounds__(256) void gather_nodes(
    const __hip_bfloat16* __restrict__ Zb,
    const int*   __restrict__ offsets,
    const int*   __restrict__ partials,
    const int2*  __restrict__ csr,
    float*       __restrict__ out,
    int N, int nb)
{
    __shared__ int sp[256];
    scan_partials_lds256(partials, nb, sp);

    const int node = blockIdx.x * 4 + (threadIdx.x >> 6);
    const int lane = threadIdx.x & 63;
    if (node >= N) return;

    const int slot = lane >> 4;
    const int q    = lane & 15;

    const int ib  = node * R;
    const int ie  = (node + 1) * R;      // valid: padded scan array covers it
    const int beg = offsets[ib] + sp[ib >> 12];
    const int end = offsets[ie] + sp[ie >> 12];

    const ushort4* Zu = reinterpret_cast<const ushort4*>(Zb);
    float4 acc = {0.f, 0.f, 0.f, 0.f};

    int  j   = beg + slot;
    int2 cur = (j < end) ? csr[j] : make_int2(0, 0);
    while (j < end) {
        const int jn  = j + 4;
        int2      nxt = (jn < end) ? csr[jn] : make_int2(0, 0);
        float     w   = __int_as_float(cur.y);
        ushort4   zu  = Zu[(size_t)cur.x * 16 + q];
        acc.x = fmaf(w, __uint_as_float((unsigned)zu.x << 16), acc.x);
        acc.y = fmaf(w, __uint_as_float((unsigned)zu.y << 16), acc.y);
        acc.z = fmaf(w, __uint_as_float((unsigned)zu.z << 16), acc.z);
        acc.w = fmaf(w, __uint_as_float((unsigned)zu.w << 16), acc.w);
        cur = nxt;
        j   = jn;
    }

#pragma unroll
    for (int off = 32; off >= 16; off >>= 1) {
        acc.x += __shfl_down(acc.x, off, 64);
        acc.y += __shfl_down(acc.y, off, 64);
        acc.z += __shfl_down(acc.z, off, 64);
        acc.w += __shfl_down(acc.w, off, 64);
    }

    if (lane < 16) {
        float4 r;
        r.x = fmaxf(acc.x, 0.f);
        r.y = fmaxf(acc.y, 0.f);
        r.z = fmaxf(acc.z, 0.f);
        r.w = fmaxf(acc.w, 0.f);
        reinterpret_cast<float4*>(out)[(size_t)node * 16 + lane] = r;
    }
}

// ---------------------------------------------------------------------------
extern "C" void kernel_launch(void* const* d_in, const int* in_sizes, int n_in,
                              void* d_out, int out_size, void* d_ws, size_t ws_size,
                              hipStream_t stream)
{
    const float* emb  = (const float*)d_in[0];  // [N, 64]
    const int*   esrc = (const int*)  d_in[1];  // [E]
    const int*   edst = (const int*)  d_in[2];  // [E]
    const float* ew   = (const float*)d_in[3];  // [E]
    const float* W    = (const float*)d_in[4];  // [64, 64]
    float*       out  = (float*)d_out;          // [N, 64]

    const int N = in_sizes[0] / D;
    const int E = in_sizes[1];

    const int M    = N * R;                     // replicated counter count
    const int nb   = (M + 4095) / 4096;         // scan chunks (<= 256)
    const int Mpad = nb * 4096;

    // Workspace layout (~22.4 MB), every segment 16 B aligned.
    char* p = (char*)d_ws;
    __hip_bfloat16* Zb = (__hip_bfloat16*)p;  p += (size_t)N * D * 2;  // 6.4 MB
    int*  counts   = (int*)p;                 p += (size_t)Mpad * 4;  // 3.2 MB
    int*  offsets  = (int*)p;                 p += (size_t)Mpad * 4;  // 3.2 MB
    int*  partials = (int*)p;                 p += 256 * 4;
    int*  rank     = (int*)p;                 p += (size_t)E * 4;     // 3.2 MB
    int2* csr      = (int2*)p;                                        // 6.4 MB

    hipMemsetAsync(counts, 0, (size_t)Mpad * sizeof(int), stream);

    const int gemmTiles   = (N + 63) / 64;
    const int countBlocks = (E + 255) / 256;
    gemm_count<<<gemmTiles + countBlocks, 256, 0, stream>>>(
        emb, W, Zb, edst, counts, rank, N, E, gemmTiles);

    scan_blocks2<<<nb, 256, 0, stream>>>(counts, offsets, partials);

    fill_csr<<<((E >> 2) + 255) / 256, 256, 0, stream>>>(
        edst, rank, esrc, ew, offsets, partials, csr, E, nb);

    gather_nodes<<<(N + 3) / 4, 256, 0, stream>>>(
        Zb, offsets, partials, csr, out, N, nb);
}